// Round 1
// baseline (270.727 us; speedup 1.0000x reference)
//
#include <hip/hip_runtime.h>
#include <stdint.h>

// SpatialAttention: B=4, C_in=256, C_out=128, N=64*64=4096
// R6: occupancy attack on k_flash. Counters showed 2 blocks/CU (grid 512 =
// exactly 2/CU), MfmaUtil 30 / VALU 35 / HBM 6.5% -> latency-bound.
// (1) KV split into QUARTERS: grid 1024 = exactly 4 blocks/CU, no tail.
// (2) LDS 54272->37888 B so 4 blocks fit: V single-buffered. Legal since
//     PV is channel-split -> each wave reads only V rows IT staged (no
//     cross-wave V handoff); V(mt+1) issue moves to after PV(mt), covered
//     by next iter's QK+softmax.
// (3) Counted-vmcnt schedule (3 raw barriers/iter): vmcnt(4) before B1
//     (K landed, V in flight), lgkm(0)+vmcnt(2) before B2 (P visible, V
//     landed), lgkm(0) before B3 (P/V LDS reads drained before overwrite
//     -- this drain is what makes raw barriers race-free here).
// Merge now sums 4 partials (per-partial magnitude halves -> bf16 quantum
// halves -> net rounding error ~unchanged).

#define B_ 4
#define C_ 256
#define O_ 128
#define N_ 4096

#define AP 72  // proj LDS pitch (bf16 elems)
#define PP 40  // flash P-tile pitch (32 cols + pad)

typedef float v4f __attribute__((ext_vector_type(4)));
typedef short v8s __attribute__((ext_vector_type(8)));
typedef _Float16 v8h __attribute__((ext_vector_type(8)));
typedef uint32_t u32;
typedef unsigned short u16;

__device__ __forceinline__ u16 bf16_rne(float f) {
  u32 u = __builtin_bit_cast(u32, f);
  u += 0x7fffu + ((u >> 16) & 1u);
  return (u16)(u >> 16);
}
__device__ __forceinline__ float bf16_f(u16 s) {
  u32 u = ((u32)s) << 16;
  return __builtin_bit_cast(float, u);
}
__device__ __forceinline__ u16 f16_rne(float f) {
  _Float16 h = (_Float16)f;
  return __builtin_bit_cast(u16, h);
}
__device__ __forceinline__ float f16_f(u16 s) {
  return (float)__builtin_bit_cast(_Float16, s);
}
__device__ __forceinline__ v4f mfma16(v8s a, v8s b, v4f c) {
  return __builtin_amdgcn_mfma_f32_16x16x32_bf16(a, b, c, 0, 0, 0);
}
__device__ __forceinline__ v4f mfma16h(v8h a, v8h b, v4f c) {
  return __builtin_amdgcn_mfma_f32_16x16x32_f16(a, b, c, 0, 0, 0);
}
__device__ __forceinline__ void gl16(const u16* g, u16* l) {
  __builtin_amdgcn_global_load_lds(
      (const __attribute__((address_space(1))) u32*)g,
      (__attribute__((address_space(3))) u32*)l, 16, 0, 0);
}
template <int CTRL>
__device__ __forceinline__ float dppadd(float x) {
  int yi = __builtin_amdgcn_update_dpp(0, __builtin_bit_cast(int, x), CTRL,
                                       0xf, 0xf, true);
  return x + __builtin_bit_cast(float, yi);
}
__device__ __forceinline__ float sum16(float x) {
  x = dppadd<0xB1>(x);   // xor 1
  x = dppadd<0x4E>(x);   // xor 2
  x = dppadd<0x141>(x);  // xor 4 (row_half_mirror)
  x = dppadd<0x140>(x);  // xor 8 (row_mirror)
  return x;
}

// ------------- merged Q/K projection (+V cast on the K instance) ------------
// blocks 0..255: Q = p*Wq+bq -> fp16 hi/lo planes. 256..511: K = b*Wk+bk ->
// fp16 hi plane only, plus bf16 cast of b into Vbf [B][C][N].
// GEMM internals: split-bf16 3-pass (err ~1e-4).
__global__ __launch_bounds__(256) void k_proj(
    const float* __restrict__ Xp, const float* __restrict__ Wq,
    const float* __restrict__ bq, const float* __restrict__ Xb,
    const float* __restrict__ Wk, const float* __restrict__ bk,
    u16* __restrict__ Qh, u16* __restrict__ Ql, u16* __restrict__ Kh,
    u16* __restrict__ Vbf) {
  __shared__ __align__(16) short ah[64 * AP];
  __shared__ __align__(16) short al[64 * AP];
  __shared__ __align__(16) short wh[128 * AP];
  __shared__ __align__(16) short wl[128 * AP];
  const int tid = threadIdx.x;
  const int inst = blockIdx.x >> 8;  // 0 = Q, 1 = K (block-uniform)
  const float* X = inst ? Xb : Xp;
  const float* W = inst ? Wk : Wq;
  const float* bias = inst ? bk : bq;
  const int b = (blockIdx.x >> 6) & 3;
  const int n0 = (blockIdx.x & 63) << 6;
  const int w = tid >> 6, lane = tid & 63, l15 = lane & 15, quad = lane >> 4;
  v4f acc[8];
#pragma unroll
  for (int t = 0; t < 8; t++) acc[t] = (v4f){0.f, 0.f, 0.f, 0.f};

  for (int c0 = 0; c0 < C_; c0 += 64) {
    __syncthreads();
    {  // stage A: transpose X[c][n]->lds[n][c], split hi/lo (+ fused V cast)
      const int c = tid >> 2, nch = (tid & 3) << 4;
      const float* s = X + ((size_t)(b * C_ + c0 + c)) * N_ + n0 + nch;
      float4 f0 = ((const float4*)s)[0], f1 = ((const float4*)s)[1],
             f2 = ((const float4*)s)[2], f3 = ((const float4*)s)[3];
      float v[16] = {f0.x, f0.y, f0.z, f0.w, f1.x, f1.y, f1.z, f1.w,
                     f2.x, f2.y, f2.z, f2.w, f3.x, f3.y, f3.z, f3.w};
      u16 hh[16];
#pragma unroll
      for (int j = 0; j < 16; j++) {
        u16 h = bf16_rne(v[j]);
        u16 l = bf16_rne(v[j] - bf16_f(h));
        hh[j] = h;
        ah[(nch + j) * AP + c] = (short)h;
        al[(nch + j) * AP + c] = (short)l;
      }
      if (inst) {
        u32 pk[8];
#pragma unroll
        for (int jj = 0; jj < 8; jj++)
          pk[jj] = (u32)hh[2 * jj] | ((u32)hh[2 * jj + 1] << 16);
        u16* vd = Vbf + ((size_t)(b * C_ + c0 + c)) * N_ + n0 + nch;
        ((uint4*)vd)[0] = make_uint4(pk[0], pk[1], pk[2], pk[3]);
        ((uint4*)vd)[1] = make_uint4(pk[4], pk[5], pk[6], pk[7]);
      }
    }
    {  // stage W chunk [128 o][64 c], split hi/lo
      const int o = tid >> 1, cch = (tid & 1) << 5;
      const float* s = W + (size_t)o * C_ + c0 + cch;
#pragma unroll
      for (int jj = 0; jj < 8; jj++) {
        float4 f = ((const float4*)s)[jj];
        float v[4] = {f.x, f.y, f.z, f.w};
#pragma unroll
        for (int j = 0; j < 4; j++) {
          u16 h = bf16_rne(v[j]);
          u16 l = bf16_rne(v[j] - bf16_f(h));
          wh[o * AP + cch + jj * 4 + j] = (short)h;
          wl[o * AP + cch + jj * 4 + j] = (short)l;
        }
      }
    }
    __syncthreads();
#pragma unroll
    for (int s = 0; s < 2; s++) {
      v8s a_h = *(const v8s*)&ah[(16 * w + l15) * AP + 32 * s + 8 * quad];
      v8s a_l = *(const v8s*)&al[(16 * w + l15) * AP + 32 * s + 8 * quad];
#pragma unroll
      for (int to = 0; to < 8; to++) {
        v8s b_h = *(const v8s*)&wh[(16 * to + l15) * AP + 32 * s + 8 * quad];
        v8s b_l = *(const v8s*)&wl[(16 * to + l15) * AP + 32 * s + 8 * quad];
        acc[to] = mfma16(a_h, b_h, acc[to]);
        acc[to] = mfma16(a_h, b_l, acc[to]);
        acc[to] = mfma16(a_l, b_h, acc[to]);
      }
    }
  }
#pragma unroll
  for (int to = 0; to < 8; to++) {
    const int o = 16 * to + l15;
    const float bv = bias[o];
#pragma unroll
    for (int r = 0; r < 4; r++) {
      const int n = n0 + 16 * w + 4 * quad + r;  // C/D row = quad*4+reg
      float v = acc[to][r] + bv;
      const size_t idx = (size_t)(b * N_ + n) * O_ + o;
      if (!inst) {
        u16 h = f16_rne(v);
        Qh[idx] = h;
        Ql[idx] = f16_rne(v - f16_f(h));
      } else {
        Kh[idx] = f16_rne(v);
      }
    }
  }
}

// ---------------- fused flash attention (partial over a KV quarter) ---------
// block = (batch, 64-row Q tile, KV quarter); 4 waves, 32 KV tiles of 32.
// QK: wave w owns Q rows 16w..16w+15 (2-pass fp16). PV: wave w owns channels
// 64w..64w+63 for all 64 rows; P crosses waves via LDS; V is wave-local.
// LDS 37888 B -> 4 blocks/CU (grid 1024 = exactly 4/CU, no tail).
__global__ __launch_bounds__(256, 4) void k_flash(
    const u16* __restrict__ Qh, const u16* __restrict__ Ql,
    const u16* __restrict__ Khp, const u16* __restrict__ Vbf,
    u16* __restrict__ Opart, float* __restrict__ lpart) {
  // shorts: K dbuf [2][32][128] fp16 @0, V [256][32] bf16 @8192,
  //         P [64][PP] @16384 (2560 shorts). total 18944 shorts = 37888 B.
  __shared__ __align__(16) short smem[18944];
  short* Pt = smem + 16384;

  const int tid = threadIdx.x;
  const int w = tid >> 6, lane = tid & 63, l15 = lane & 15, quad = lane >> 4;
  const int h = blockIdx.x & 3;
  const int qt = (blockIdx.x >> 2) & 63;
  const int b = blockIdx.x >> 8;
  const int n0 = qt << 6;
  const int tok0 = h << 10;

  const u16* khb = Khp + (size_t)b * N_ * O_;
  const u16* vb = Vbf + (size_t)b * C_ * N_;

  // Q fragments (A-layout: row=lane&15, k=32s+8*quad+j), fp16 hi/lo
  v8h qh[4], ql[4];
  {
    const u16* qrh = Qh + (size_t)(b * N_ + n0 + 16 * w + l15) * O_;
    const u16* qrl = Ql + (size_t)(b * N_ + n0 + 16 * w + l15) * O_;
#pragma unroll
    for (int s = 0; s < 4; s++) {
      qh[s] = *(const v8h*)(qrh + 32 * s + 8 * quad);
      ql[s] = *(const v8h*)(qrl + 32 * s + 8 * quad);
    }
  }

  v4f oacc[16];  // [rw][cg]: rows 16rw+4quad+r, channels 64w+16cg+l15
#pragma unroll
  for (int t = 0; t < 16; t++) oacc[t] = (v4f){0.f, 0.f, 0.f, 0.f};
  float lstate[4] = {0.f, 0.f, 0.f, 0.f};

  auto stageK = [&](int mtn, int bi) {
    const int m0n = tok0 + (mtn << 5);
    short* kd = smem + bi * 4096;
#pragma unroll
    for (int i = 0; i < 2; i++) {  // K fp16: 4 rows/issue, 8 rows/wave
      const int R = 8 * w + 4 * i;
      const int rl = R + (lane >> 4);
      const int cg = (lane & 15) ^ (rl & 15);
      gl16(khb + ((size_t)(m0n + rl) << 7) + (cg << 3), (u16*)(kd + (R << 7)));
    }
  };
  auto stageV = [&](int mtn) {
    const int m0n = tok0 + (mtn << 5);
    short* vd = smem + 8192;
#pragma unroll
    for (int i = 0; i < 4; i++) {  // V bf16: 16 chan-rows/issue, 64/wave
      const int R = 64 * w + 16 * i;
      const int rl = R + (lane >> 2);
      const int cg = (lane & 3) ^ ((rl >> 1) & 3);
      gl16(vb + (size_t)rl * N_ + m0n + (cg << 3), (u16*)(vd + (R << 5)));
    }
  };

  stageK(0, 0);  // queue invariant at loop top: [K(mt) x2, V(mt) x4]
  stageV(0);

#pragma unroll 1
  for (int mt = 0; mt < 32; mt++) {
    const int pr = mt & 1;
    // W1/B1: vmcnt(4) -> K(mt) landed (V(mt) may still be in flight).
    __builtin_amdgcn_s_waitcnt(0x0F74);
    asm volatile("s_barrier" ::: "memory");
    if (mt + 1 < 32) stageK(mt + 1, 1 - pr);  // K buf 1-pr: readers drained
                                              // 2 barriers ago (W2 lgkm0)
    const short* kc = smem + pr * 4096;
    const short* vc = smem + 8192;

    // QK: e = (qh+ql) . k, 2-pass fp16, two acc chains for ILP
    v4f eh[2], el[2];
#pragma unroll
    for (int t = 0; t < 2; t++) {
      eh[t] = (v4f){0.f, 0.f, 0.f, 0.f};
      el[t] = (v4f){0.f, 0.f, 0.f, 0.f};
    }
#pragma unroll
    for (int s = 0; s < 4; s++) {
#pragma unroll
      for (int t = 0; t < 2; t++) {
        const int off = ((16 * t + l15) << 7) + (((4 * s + quad) ^ l15) << 3);
        const v8h kf = *(const v8h*)&kc[off];
        eh[t] = mfma16h(qh[s], kf, eh[t]);
        el[t] = mfma16h(ql[s], kf, el[t]);
      }
    }

    // no-max softmax: p=exp(e); DPP 16-lane row sums; write P tile (shared)
#pragma unroll
    for (int r = 0; r < 4; r++) {
      float p0 = __expf(eh[0][r] + el[0][r]);
      float p1 = __expf(eh[1][r] + el[1][r]);
      lstate[r] += sum16(p0 + p1);
      Pt[(16 * w + 4 * quad + r) * PP + l15] = (short)bf16_rne(p0);
      Pt[(16 * w + 4 * quad + r) * PP + 16 + l15] = (short)bf16_rne(p1);
    }
    // W2/B2: P written+visible (lgkm0); own V(mt) landed (vmcnt: allow the
    // 2 K(mt+1) loads to stay in flight; drain fully on last iter).
    if (mt + 1 < 32)
      __builtin_amdgcn_s_waitcnt(0x0072);  // lgkmcnt(0) + vmcnt(2)
    else
      __builtin_amdgcn_s_waitcnt(0x0070);  // lgkmcnt(0) + vmcnt(0)
    asm volatile("s_barrier" ::: "memory");

    // PV channel-split: oacc[rw][cg] += P(rows 16rw) * V(ch 64w+16cg)
    v8s af[4];
#pragma unroll
    for (int rw = 0; rw < 4; rw++)
      af[rw] = *(const v8s*)&Pt[(16 * rw + l15) * PP + 8 * quad];
#pragma unroll
    for (int cg = 0; cg < 4; cg++) {
      const int ch = 64 * w + 16 * cg + l15;
      const int voff = (ch << 5) + ((quad ^ ((ch >> 1) & 3)) << 3);
      const v8s vf = *(const v8s*)&vc[voff];
#pragma unroll
      for (int rw = 0; rw < 4; rw++)
        oacc[rw * 4 + cg] = mfma16(af[rw], vf, oacc[rw * 4 + cg]);
    }

    // W3/B3: drain own P/V ds_reads (lgkm0) so the raw barrier guarantees
    // no in-flight LDS read when V buf / P tile are overwritten next.
    __builtin_amdgcn_s_waitcnt(0xC07F);
    asm volatile("s_barrier" ::: "memory");
    if (mt + 1 < 32) stageV(mt + 1);  // V is wave-local: only this wave
                                      // reads the rows it stages
  }

  // epilogue: pack bf16 partial O into LDS [256][72], write l, copy out
  __syncthreads();
  u16* outx = (u16*)smem;  // pitch 72 shorts (144 B, 16B-aligned rows)
#pragma unroll
  for (int rw = 0; rw < 4; rw++)
#pragma unroll
    for (int cg = 0; cg < 4; cg++) {
      const int ch = 64 * w + 16 * cg + l15;
      const v4f o = oacc[rw * 4 + cg];
      u32* q = (u32*)outx;
      const int base = ch * 36 + 8 * rw + 2 * quad;
      q[base] = (u32)bf16_rne(o[0]) | ((u32)bf16_rne(o[1]) << 16);
      q[base + 1] = (u32)bf16_rne(o[2]) | ((u32)bf16_rne(o[3]) << 16);
    }
  if (l15 == 0) {
#pragma unroll
    for (int r = 0; r < 4; r++)
      lpart[(size_t)blockIdx.x * 64 + 16 * w + 4 * quad + r] = lstate[r];
  }
  __syncthreads();
  {
    u16* od = Opart + (size_t)blockIdx.x * 16384;
    const int cr = tid >> 2, nch = (tid & 3) << 4;
#pragma unroll
    for (int it = 0; it < 4; it++) {
      const int c = cr + 64 * it;
      const u16* srcr = &outx[c * 72 + nch];
      uint4* dst = (uint4*)(od + c * 64 + nch);
      dst[0] = ((const uint4*)srcr)[0];
      dst[1] = ((const uint4*)srcr)[1];
    }
  }
}

// ---------------- merge KV quarters: out = (ΣO_i)/(Σl_i) --------------------
__global__ __launch_bounds__(256) void k_merge(const u16* __restrict__ Opart,
                                               const float* __restrict__ lpart,
                                               float* __restrict__ out) {
  const int idx = blockIdx.x * 256 + threadIdx.x;
  const int e4 = idx << 2;  // flat out index: b*2^20 + c*2^12 + n
  const int b = e4 >> 20;
  const int c = (e4 >> 12) & 255;
  const int n = e4 & 4095;
  const int qt = n >> 6, row = n & 63;
  const int g = (b * 64 + qt) * 4;
  const u16* q0 = Opart + (size_t)g * 16384 + c * 64 + row;
  ushort4 a0 = *(const ushort4*)q0;
  ushort4 a1 = *(const ushort4*)(q0 + 16384);
  ushort4 a2 = *(const ushort4*)(q0 + 32768);
  ushort4 a3 = *(const ushort4*)(q0 + 49152);
  const float* lb = lpart + (size_t)g * 64 + row;
  float4 l0 = *(const float4*)lb;
  float4 l1 = *(const float4*)(lb + 64);
  float4 l2 = *(const float4*)(lb + 128);
  float4 l3 = *(const float4*)(lb + 192);
  float4 o;
  o.x = (bf16_f(a0.x) + bf16_f(a1.x) + bf16_f(a2.x) + bf16_f(a3.x)) /
        (l0.x + l1.x + l2.x + l3.x);
  o.y = (bf16_f(a0.y) + bf16_f(a1.y) + bf16_f(a2.y) + bf16_f(a3.y)) /
        (l0.y + l1.y + l2.y + l3.y);
  o.z = (bf16_f(a0.z) + bf16_f(a1.z) + bf16_f(a2.z) + bf16_f(a3.z)) /
        (l0.z + l1.z + l2.z + l3.z);
  o.w = (bf16_f(a0.w) + bf16_f(a1.w) + bf16_f(a2.w) + bf16_f(a3.w)) /
        (l0.w + l1.w + l2.w + l3.w);
  *(float4*)(out + e4) = o;
}

extern "C" void kernel_launch(void* const* d_in, const int* in_sizes, int n_in,
                              void* d_out, int out_size, void* d_ws, size_t ws_size,
                              hipStream_t stream) {
  const float* p = (const float*)d_in[0];
  const float* bb = (const float*)d_in[1];
  const float* Wq = (const float*)d_in[2];
  const float* bq = (const float*)d_in[3];
  const float* Wk = (const float*)d_in[4];
  const float* bk = (const float*)d_in[5];
  float* out = (float*)d_out;

  const size_t plane = (size_t)B_ * N_ * O_;  // 2,097,152 u16
  u16* Qh = (u16*)d_ws;
  u16* Ql = Qh + plane;
  u16* Kh = Ql + plane;
  u16* Vbf = Kh + plane;                         // B*C*N u16 = 2 planes
  u16* Opart = Vbf + 2 * plane;                  // 1024*16384 u16 = 33.55 MB
  float* lpart = (float*)(Opart + (size_t)1024 * 16384);  // 1024*64 fp32
  // total ws use ~= 54.8 MB

  hipLaunchKernelGGL(k_proj, dim3(512), dim3(256), 0, stream, p, Wq, bq, bb,
                     Wk, bk, Qh, Ql, Kh, Vbf);
  hipLaunchKernelGGL(k_flash, dim3(B_ * 64 * 4), dim3(256), 0, stream, Qh, Ql,
                     Kh, Vbf, Opart, lpart);
  hipLaunchKernelGGL(k_merge, dim3((B_ * C_ * N_) / (256 * 4)), dim3(256), 0,
                     stream, Opart, lpart, out);
}

// Round 2
// 193.440 us; speedup vs baseline: 1.3995x; 1.3995x over previous
//
#include <hip/hip_runtime.h>
#include <stdint.h>

// SpatialAttention: B=4, C_in=256, C_out=128, N=64*64=4096
// R7: occupancy via 8-wave blocks, keeping R5's streaming structure.
// R6 post-mortem: KV-quarters + single-buffered V cut prefetch distance ->
// stalls -> inter-block drift -> L2 stopped absorbing re-reads (FETCH 33MB
// -> 208MB, BW 1.56TB/s) -> 270us. Lesson: never buy occupancy with
// prefetch distance or streaming synchrony.
// R7 design:
// (1) 512-thread blocks (8 waves), 64-token tiles, 32 iters. Grid stays 512
//     (KV halves) = 2 blocks/CU but 16 waves/CU (4/SIMD), 2x R5. Barriers
//     per token halve.
// (2) V never touches LDS: PV is channel-split (wave owns 32 ch), so each
//     lane loads its V B-fragment straight from global (one 64B line per
//     ch row, L2-resident). Issued right after B1 -> full QK+softmax of
//     latency cover; compiler's counted vmcnt leaves K DMA in flight.
//     LDS = K dbuf 32KB + P 9KB = 41984B -> 2 blocks/CU with slack.
// (3) XCD-aware decode: (b,h)=bid&7, qt=bid>>3 -> each XCD owns exactly one
//     (batch, KV-half) stream = 1.5MB < 4MB L2 -> K/V re-reads are L2 hits
//     regardless of drift. Kills the R6 failure mode structurally.

#define B_ 4
#define C_ 256
#define O_ 128
#define N_ 4096

#define AP 72   // proj LDS pitch (bf16 elems)
#define PFP 72  // flash P-tile pitch (64 cols + 8 pad)

typedef float v4f __attribute__((ext_vector_type(4)));
typedef short v8s __attribute__((ext_vector_type(8)));
typedef _Float16 v8h __attribute__((ext_vector_type(8)));
typedef uint32_t u32;
typedef unsigned short u16;

__device__ __forceinline__ u16 bf16_rne(float f) {
  u32 u = __builtin_bit_cast(u32, f);
  u += 0x7fffu + ((u >> 16) & 1u);
  return (u16)(u >> 16);
}
__device__ __forceinline__ float bf16_f(u16 s) {
  u32 u = ((u32)s) << 16;
  return __builtin_bit_cast(float, u);
}
__device__ __forceinline__ u16 f16_rne(float f) {
  _Float16 h = (_Float16)f;
  return __builtin_bit_cast(u16, h);
}
__device__ __forceinline__ float f16_f(u16 s) {
  return (float)__builtin_bit_cast(_Float16, s);
}
__device__ __forceinline__ v4f mfma16(v8s a, v8s b, v4f c) {
  return __builtin_amdgcn_mfma_f32_16x16x32_bf16(a, b, c, 0, 0, 0);
}
__device__ __forceinline__ v4f mfma16h(v8h a, v8h b, v4f c) {
  return __builtin_amdgcn_mfma_f32_16x16x32_f16(a, b, c, 0, 0, 0);
}
__device__ __forceinline__ void gl16(const u16* g, u16* l) {
  __builtin_amdgcn_global_load_lds(
      (const __attribute__((address_space(1))) u32*)g,
      (__attribute__((address_space(3))) u32*)l, 16, 0, 0);
}
template <int CTRL>
__device__ __forceinline__ float dppadd(float x) {
  int yi = __builtin_amdgcn_update_dpp(0, __builtin_bit_cast(int, x), CTRL,
                                       0xf, 0xf, true);
  return x + __builtin_bit_cast(float, yi);
}
__device__ __forceinline__ float sum16(float x) {
  x = dppadd<0xB1>(x);   // xor 1
  x = dppadd<0x4E>(x);   // xor 2
  x = dppadd<0x141>(x);  // xor 4 (row_half_mirror)
  x = dppadd<0x140>(x);  // xor 8 (row_mirror)
  return x;
}

// ------------- merged Q/K projection (+V cast on the K instance) ------------
// blocks 0..255: Q = p*Wq+bq -> fp16 hi/lo planes. 256..511: K = b*Wk+bk ->
// fp16 hi plane only, plus bf16 cast of b into Vbf [B][C][N].
// GEMM internals: split-bf16 3-pass (err ~1e-4).
__global__ __launch_bounds__(256) void k_proj(
    const float* __restrict__ Xp, const float* __restrict__ Wq,
    const float* __restrict__ bq, const float* __restrict__ Xb,
    const float* __restrict__ Wk, const float* __restrict__ bk,
    u16* __restrict__ Qh, u16* __restrict__ Ql, u16* __restrict__ Kh,
    u16* __restrict__ Vbf) {
  __shared__ __align__(16) short ah[64 * AP];
  __shared__ __align__(16) short al[64 * AP];
  __shared__ __align__(16) short wh[128 * AP];
  __shared__ __align__(16) short wl[128 * AP];
  const int tid = threadIdx.x;
  const int inst = blockIdx.x >> 8;  // 0 = Q, 1 = K (block-uniform)
  const float* X = inst ? Xb : Xp;
  const float* W = inst ? Wk : Wq;
  const float* bias = inst ? bk : bq;
  const int b = (blockIdx.x >> 6) & 3;
  const int n0 = (blockIdx.x & 63) << 6;
  const int w = tid >> 6, lane = tid & 63, l15 = lane & 15, quad = lane >> 4;
  v4f acc[8];
#pragma unroll
  for (int t = 0; t < 8; t++) acc[t] = (v4f){0.f, 0.f, 0.f, 0.f};

  for (int c0 = 0; c0 < C_; c0 += 64) {
    __syncthreads();
    {  // stage A: transpose X[c][n]->lds[n][c], split hi/lo (+ fused V cast)
      const int c = tid >> 2, nch = (tid & 3) << 4;
      const float* s = X + ((size_t)(b * C_ + c0 + c)) * N_ + n0 + nch;
      float4 f0 = ((const float4*)s)[0], f1 = ((const float4*)s)[1],
             f2 = ((const float4*)s)[2], f3 = ((const float4*)s)[3];
      float v[16] = {f0.x, f0.y, f0.z, f0.w, f1.x, f1.y, f1.z, f1.w,
                     f2.x, f2.y, f2.z, f2.w, f3.x, f3.y, f3.z, f3.w};
      u16 hh[16];
#pragma unroll
      for (int j = 0; j < 16; j++) {
        u16 h = bf16_rne(v[j]);
        u16 l = bf16_rne(v[j] - bf16_f(h));
        hh[j] = h;
        ah[(nch + j) * AP + c] = (short)h;
        al[(nch + j) * AP + c] = (short)l;
      }
      if (inst) {
        u32 pk[8];
#pragma unroll
        for (int jj = 0; jj < 8; jj++)
          pk[jj] = (u32)hh[2 * jj] | ((u32)hh[2 * jj + 1] << 16);
        u16* vd = Vbf + ((size_t)(b * C_ + c0 + c)) * N_ + n0 + nch;
        ((uint4*)vd)[0] = make_uint4(pk[0], pk[1], pk[2], pk[3]);
        ((uint4*)vd)[1] = make_uint4(pk[4], pk[5], pk[6], pk[7]);
      }
    }
    {  // stage W chunk [128 o][64 c], split hi/lo
      const int o = tid >> 1, cch = (tid & 1) << 5;
      const float* s = W + (size_t)o * C_ + c0 + cch;
#pragma unroll
      for (int jj = 0; jj < 8; jj++) {
        float4 f = ((const float4*)s)[jj];
        float v[4] = {f.x, f.y, f.z, f.w};
#pragma unroll
        for (int j = 0; j < 4; j++) {
          u16 h = bf16_rne(v[j]);
          u16 l = bf16_rne(v[j] - bf16_f(h));
          wh[o * AP + cch + jj * 4 + j] = (short)h;
          wl[o * AP + cch + jj * 4 + j] = (short)l;
        }
      }
    }
    __syncthreads();
#pragma unroll
    for (int s = 0; s < 2; s++) {
      v8s a_h = *(const v8s*)&ah[(16 * w + l15) * AP + 32 * s + 8 * quad];
      v8s a_l = *(const v8s*)&al[(16 * w + l15) * AP + 32 * s + 8 * quad];
#pragma unroll
      for (int to = 0; to < 8; to++) {
        v8s b_h = *(const v8s*)&wh[(16 * to + l15) * AP + 32 * s + 8 * quad];
        v8s b_l = *(const v8s*)&wl[(16 * to + l15) * AP + 32 * s + 8 * quad];
        acc[to] = mfma16(a_h, b_h, acc[to]);
        acc[to] = mfma16(a_h, b_l, acc[to]);
        acc[to] = mfma16(a_l, b_h, acc[to]);
      }
    }
  }
#pragma unroll
  for (int to = 0; to < 8; to++) {
    const int o = 16 * to + l15;
    const float bv = bias[o];
#pragma unroll
    for (int r = 0; r < 4; r++) {
      const int n = n0 + 16 * w + 4 * quad + r;  // C/D row = quad*4+reg
      float v = acc[to][r] + bv;
      const size_t idx = (size_t)(b * N_ + n) * O_ + o;
      if (!inst) {
        u16 h = f16_rne(v);
        Qh[idx] = h;
        Ql[idx] = f16_rne(v - f16_f(h));
      } else {
        Kh[idx] = f16_rne(v);
      }
    }
  }
}

// ---------------- fused flash attention (partial over a KV half) ------------
// 8 waves / 512 threads; block = (batch, 64-row Q tile, KV half) decoded so
// XCD x owns the single (b,h)=(x>>1, x&1) stream. 32 iters of 64 tokens.
// QK: wave w owns rows 16*(w&3), tokens 32*(w>>2)+[0,32). PV: wave w owns
// channels 32w..32w+31 for all 64 rows; P crosses waves via LDS; V comes
// straight from global into B-fragments (wave-local channels).
__global__ __launch_bounds__(512, 4) void k_flash(
    const u16* __restrict__ Qh, const u16* __restrict__ Ql,
    const u16* __restrict__ Khp, const u16* __restrict__ Vbf,
    u16* __restrict__ Opart, float* __restrict__ lpart) {
  // shorts: K dbuf [2][64][128] fp16 @0 (16384), P [64][PFP] @16384 (4608)
  // total 20992 shorts = 41984 B -> 2 blocks/CU (83968 <= 163840).
  __shared__ __align__(16) short smem[20992];
  short* Pt = smem + 16384;

  const int tid = threadIdx.x;
  const int w = tid >> 6, lane = tid & 63, l15 = lane & 15, quad = lane >> 4;
  const int wr = w & 3, wh2 = w >> 2;
  const int xcd = blockIdx.x & 7;
  const int b = xcd >> 1, h = xcd & 1;  // XCD owns one (b, half) stream
  const int qt = blockIdx.x >> 3;
  const int n0 = qt << 6;
  const int tok0 = h << 11;
  const int og = (b << 7) + (qt << 1) + h;  // output group (merge layout)

  const u16* khb = Khp + (size_t)b * N_ * O_;
  const u16* vb = Vbf + (size_t)b * C_ * N_;

  // Q fragments (A-layout: row=lane&15, k=32s+8*quad+j), fp16 hi/lo
  v8h qh[4], ql[4];
  {
    const u16* qrh = Qh + (size_t)(b * N_ + n0 + 16 * wr + l15) * O_;
    const u16* qrl = Ql + (size_t)(b * N_ + n0 + 16 * wr + l15) * O_;
#pragma unroll
    for (int s = 0; s < 4; s++) {
      qh[s] = *(const v8h*)(qrh + 32 * s + 8 * quad);
      ql[s] = *(const v8h*)(qrl + 32 * s + 8 * quad);
    }
  }

  v4f oacc[8];  // [rw][cg]: rows 16rw+4quad+r, channels 32w+16cg+l15
#pragma unroll
  for (int t = 0; t < 8; t++) oacc[t] = (v4f){0.f, 0.f, 0.f, 0.f};
  float lstate[4] = {0.f, 0.f, 0.f, 0.f};

  auto stageK = [&](int mtn, int bi) {
    const int m0n = tok0 + (mtn << 6);
    short* kd = smem + bi * 8192;
#pragma unroll
    for (int i = 0; i < 2; i++) {  // 4 rows/issue, 8 rows/wave, 64 rows total
      const int R = 8 * w + 4 * i;
      const int rl = R + (lane >> 4);
      const int cg = (lane & 15) ^ (rl & 15);
      gl16(khb + ((size_t)(m0n + rl) << 7) + (cg << 3), (u16*)(kd + (R << 7)));
    }
  };

  stageK(0, 0);  // queue invariant at loop top: [K(mt) x2]

  // V fragment base: ch row = 32w+l15 (+16 for cg=1), token col 8*quad
  const u16* vrow = vb + (size_t)(32 * w + l15) * N_ + (quad << 3);

#pragma unroll 1
  for (int mt = 0; mt < 32; mt++) {
    const int pr = mt & 1;
    const int m0 = tok0 + (mt << 6);
    // B1: full drain (vmcnt0+lgkm0) -> K(mt) staged+visible; prev iter's
    // P reads drained so softmax below may overwrite P.
    __syncthreads();

    // V(mt) B-frags straight from global (wave-local channels). Issued
    // first so the compiler's pre-PV wait is vmcnt(2) -> K DMA stays in
    // flight. Latency covered by stageK issue + QK + softmax.
    v8s vfr[2][2];
#pragma unroll
    for (int cg = 0; cg < 2; cg++)
#pragma unroll
      for (int s = 0; s < 2; s++)
        vfr[cg][s] =
            *(const v8s*)(vrow + (size_t)(cg << 4) * N_ + m0 + (s << 5));

    if (mt + 1 < 32) stageK(mt + 1, 1 - pr);  // K buf 1-pr: readers drained
                                              // at B1 of this iter
    const short* kc = smem + pr * 8192;

    // QK: e = (qh+ql) . k, 2-pass fp16; wave's tokens = m0+32*wh2+[0,32)
    v4f eh[2], el[2];
#pragma unroll
    for (int t = 0; t < 2; t++) {
      eh[t] = (v4f){0.f, 0.f, 0.f, 0.f};
      el[t] = (v4f){0.f, 0.f, 0.f, 0.f};
    }
#pragma unroll
    for (int s = 0; s < 4; s++) {
#pragma unroll
      for (int t = 0; t < 2; t++) {
        const int row = (wh2 << 5) + (t << 4) + l15;
        const int off = (row << 7) + (((4 * s + quad) ^ l15) << 3);
        const v8h kf = *(const v8h*)&kc[off];
        eh[t] = mfma16h(qh[s], kf, eh[t]);
        el[t] = mfma16h(ql[s], kf, el[t]);
      }
    }

    // no-max softmax: p=exp(e); DPP 16-lane sums; write P tile (shared)
#pragma unroll
    for (int r = 0; r < 4; r++) {
      float p0 = __expf(eh[0][r] + el[0][r]);
      float p1 = __expf(eh[1][r] + el[1][r]);
      lstate[r] += sum16(p0 + p1);
      const int prow = ((wr << 4) + 4 * quad + r) * PFP + (wh2 << 5);
      Pt[prow + l15] = (short)bf16_rne(p0);
      Pt[prow + 16 + l15] = (short)bf16_rne(p1);
    }
    // B2: P handoff across waves. lgkm-only wait + raw barrier so the
    // staged K prefetch (vmcnt queue) is NOT drained mid-iter.
    __builtin_amdgcn_s_waitcnt(0xC07F);  // lgkmcnt(0)
    asm volatile("s_barrier" ::: "memory");

    // PV channel-split: oacc[rw][cg] += P(rows 16rw, k=32s..) * V(frag)
#pragma unroll
    for (int s = 0; s < 2; s++) {
      v8s af[4];
#pragma unroll
      for (int rw = 0; rw < 4; rw++)
        af[rw] =
            *(const v8s*)&Pt[((rw << 4) + l15) * PFP + (s << 5) + (quad << 3)];
#pragma unroll
      for (int cg = 0; cg < 2; cg++)
#pragma unroll
        for (int rw = 0; rw < 4; rw++)
          oacc[rw * 2 + cg] = mfma16(af[rw], vfr[cg][s], oacc[rw * 2 + cg]);
    }
  }

  // epilogue: pack bf16 partial O into LDS [256][72], write l, copy out
  __syncthreads();
  u16* outx = (u16*)smem;  // pitch 72 shorts (144 B, 16B-aligned rows)
#pragma unroll
  for (int rw = 0; rw < 4; rw++)
#pragma unroll
    for (int cg = 0; cg < 2; cg++) {
      const int ch = (w << 5) + (cg << 4) + l15;
      const v4f o = oacc[rw * 2 + cg];
      u32* q = (u32*)outx;
      const int base = ch * 36 + (rw << 3) + (quad << 1);
      q[base] = (u32)bf16_rne(o[0]) | ((u32)bf16_rne(o[1]) << 16);
      q[base + 1] = (u32)bf16_rne(o[2]) | ((u32)bf16_rne(o[3]) << 16);
    }
  if (l15 == 0) {
#pragma unroll
    for (int r = 0; r < 4; r++)
      lpart[(size_t)og * 128 + (wh2 << 6) + (wr << 4) + 4 * quad + r] =
          lstate[r];
  }
  __syncthreads();
  {
    u16* od = Opart + (size_t)og * 16384;
    const int cr = tid >> 3, col = (tid & 7) << 3;
#pragma unroll
    for (int it = 0; it < 4; it++) {
      const int c = cr + 64 * it;
      *(uint4*)(od + c * 64 + col) = *(const uint4*)&outx[c * 72 + col];
    }
  }
}

// ---------------- merge KV halves: out = (ΣO_i)/(Σl_i) ----------------------
// l has 4 partials per (b,qt,row): 2 halves x 2 token-subwaves.
__global__ __launch_bounds__(256) void k_merge(const u16* __restrict__ Opart,
                                               const float* __restrict__ lpart,
                                               float* __restrict__ out) {
  const int idx = blockIdx.x * 256 + threadIdx.x;
  const int e4 = idx << 2;  // flat out index: b*2^20 + c*2^12 + n
  const int b = e4 >> 20;
  const int c = (e4 >> 12) & 255;
  const int n = e4 & 4095;
  const int qt = n >> 6, row = n & 63;
  const int g2 = (b << 7) + (qt << 1);
  const u16* q0 = Opart + (size_t)g2 * 16384 + c * 64 + row;
  ushort4 a0 = *(const ushort4*)q0;
  ushort4 a1 = *(const ushort4*)(q0 + 16384);
  const float* lb = lpart + (size_t)g2 * 128 + row;
  float4 l0 = *(const float4*)lb;         // h0, subwave0
  float4 l1 = *(const float4*)(lb + 64);  // h0, subwave1
  float4 l2 = *(const float4*)(lb + 128); // h1, subwave0
  float4 l3 = *(const float4*)(lb + 192); // h1, subwave1
  float4 o;
  o.x = (bf16_f(a0.x) + bf16_f(a1.x)) / (l0.x + l1.x + l2.x + l3.x);
  o.y = (bf16_f(a0.y) + bf16_f(a1.y)) / (l0.y + l1.y + l2.y + l3.y);
  o.z = (bf16_f(a0.z) + bf16_f(a1.z)) / (l0.z + l1.z + l2.z + l3.z);
  o.w = (bf16_f(a0.w) + bf16_f(a1.w)) / (l0.w + l1.w + l2.w + l3.w);
  *(float4*)(out + e4) = o;
}

extern "C" void kernel_launch(void* const* d_in, const int* in_sizes, int n_in,
                              void* d_out, int out_size, void* d_ws, size_t ws_size,
                              hipStream_t stream) {
  const float* p = (const float*)d_in[0];
  const float* bb = (const float*)d_in[1];
  const float* Wq = (const float*)d_in[2];
  const float* bq = (const float*)d_in[3];
  const float* Wk = (const float*)d_in[4];
  const float* bk = (const float*)d_in[5];
  float* out = (float*)d_out;

  const size_t plane = (size_t)B_ * N_ * O_;  // 2,097,152 u16
  u16* Qh = (u16*)d_ws;
  u16* Ql = Qh + plane;
  u16* Kh = Ql + plane;
  u16* Vbf = Kh + plane;                         // B*C*N u16 = 2 planes
  u16* Opart = Vbf + 2 * plane;                  // 512*16384 u16 = 16.78 MB
  float* lpart = (float*)(Opart + (size_t)512 * 16384);  // 512*128 fp32
  // total ws use ~= 37.8 MB

  hipLaunchKernelGGL(k_proj, dim3(512), dim3(256), 0, stream, p, Wq, bq, bb,
                     Wk, bk, Qh, Ql, Kh, Vbf);
  hipLaunchKernelGGL(k_flash, dim3(B_ * 64 * 2), dim3(512), 0, stream, Qh, Ql,
                     Kh, Vbf, Opart, lpart);
  hipLaunchKernelGGL(k_merge, dim3((B_ * C_ * N_) / (256 * 4)), dim3(256), 0,
                     stream, Opart, lpart, out);
}